// Round 4
// baseline (214.916 us; speedup 1.0000x reference)
//
#include <hip/hip_runtime.h>
#include <hip/hip_bf16.h>

// GroupLinear: out[t] = x[t] @ w[gid(t)].T
// T=8192, G=8, K=1024, N=2048; groups = contiguous token ranges (cum end-offs).
//
// R9 = counted-vmcnt ring pipeline (T3/T4/T5), replacing the drain-0 2-barrier
// loop (3 rounds of evidence: MfmaUtil pinned at 25-27% regardless of traffic).
//  - BM=256, BN=128, BK=64; 8 waves (4M x 2N), per-wave 64x64 C.
//    Grid 16 x 40 = 640 blocks (2.5 rounds @ 1 block/CU -> best balance).
//  - A(x) read ONLY at phase 0 of each K-tile (all 8 frags -> regs), so A can
//    be staged 2 TILES AHEAD into a 4-half ring (64KB). B(w) read one nf-slice
//    per phase, staged 1 tile ahead into a 4-half ring (32KB). 96KB LDS.
//  - Race rule (applied to every stage): slot overwritten at phase p had its
//    last ds_read at phase <= p-2; readers' lgkm-wait + 2 barriers separate
//    service from overwrite. Stage schedule per K-tile kt:
//      p1: B0,B1[kt+1] | p2: A0[kt+2] | p3: A1[kt+2] + s_waitcnt vmcnt(4).
//    vmcnt(4) leaves A[kt+2]'s 4 loads IN FLIGHT across the barrier -- the
//    main loop never drains (m218: counted-vs-drain = +38-73%).
//  - 4 fine phases/K-tile, each {ds_read || stage -> barrier -> setprio(1),
//    8 MFMA, setprio(0) -> barrier} (m196: fine interleave is the lever).
//  - Swizzle/fragment/epilogue invariants byte-identical to verified R5/R8.
//  - cvt + fallback unchanged.

#define T_DIM 8192
#define G_DIM 8
#define K_DIM 1024
#define N_DIM 2048
#define MAX_PAIRS 40        // 32 m-tiles(256) + <=7 boundary dups, padded (%8==0)
#define NT (K_DIM / 64)     // 16 K-tiles

using short8  = __attribute__((ext_vector_type(8))) short;   // 8 bf16
using f32x4   = __attribute__((ext_vector_type(4))) float;
using ushort8 = __attribute__((ext_vector_type(8))) unsigned short;

typedef __attribute__((address_space(1))) void gvoid;  // global
typedef __attribute__((address_space(3))) void lvoid;  // LDS

#define FENCE() asm volatile("" ::: "memory")

// ---------------- fp32 -> bf16 convert (grid-stride, 2x unroll, nt loads) ---
__global__ __launch_bounds__(256) void cvt_kernel(const float* __restrict__ x,
                                                  const float* __restrict__ w,
                                                  ushort8* __restrict__ xb,
                                                  ushort8* __restrict__ wb,
                                                  int n8x, int n8tot) {
  const int stride = gridDim.x * blockDim.x;
  for (int i = blockIdx.x * blockDim.x + threadIdx.x; i < n8tot; i += 2 * stride) {
#pragma unroll
    for (int u = 0; u < 2; ++u) {
      const int idx = i + u * stride;
      if (idx >= n8tot) break;
      const f32x4* s; ushort8* d; int j;
      if (idx < n8x) { s = (const f32x4*)x; d = xb; j = idx; }
      else           { s = (const f32x4*)w; d = wb; j = idx - n8x; }
      f32x4 v0 = __builtin_nontemporal_load(&s[2 * j]);
      f32x4 v1 = __builtin_nontemporal_load(&s[2 * j + 1]);
      ushort8 o;
      o[0] = __builtin_bit_cast(unsigned short, __float2bfloat16(v0[0]));
      o[1] = __builtin_bit_cast(unsigned short, __float2bfloat16(v0[1]));
      o[2] = __builtin_bit_cast(unsigned short, __float2bfloat16(v0[2]));
      o[3] = __builtin_bit_cast(unsigned short, __float2bfloat16(v0[3]));
      o[4] = __builtin_bit_cast(unsigned short, __float2bfloat16(v1[0]));
      o[5] = __builtin_bit_cast(unsigned short, __float2bfloat16(v1[1]));
      o[6] = __builtin_bit_cast(unsigned short, __float2bfloat16(v1[2]));
      o[7] = __builtin_bit_cast(unsigned short, __float2bfloat16(v1[3]));
      d[j] = o;
    }
  }
}

// ---------------- grouped bf16 GEMM: 256x128 tile, ring pipeline ------------
__global__ __launch_bounds__(512, 2) void grouped_gemm_kernel(
    const __hip_bfloat16* __restrict__ xb,
    const __hip_bfloat16* __restrict__ wb,
    const int* __restrict__ offs,
    float* __restrict__ out) {
  // ---- bijective XCD swizzle: 640 = 8 XCD x 5 pairs x 16 n-blocks.
  const int v  = blockIdx.y * 16 + blockIdx.x;   // grid (16,40)
  const int c  = v & 7;
  const int l  = v >> 3;                          // 0..79
  const int p  = c * 5 + (l % 5);                 // pair 0..39
  const int nb = l / 5;                           // n-block 0..15
  const int n0 = nb * 128;

  // ---- map pair p -> (expert g, 256-row m-tile) via prefix sum of spans
  int offv[G_DIM];
#pragma unroll
  for (int i = 0; i < G_DIM; ++i) offv[i] = offs[i];

  int g = -1, tile = 0, lo = 0, hi = 0, pre = 0;
#pragma unroll
  for (int gi = 0; gi < G_DIM; ++gi) {
    const int lb = gi ? offv[gi - 1] : 0;
    const int hb = offv[gi];
    const int t0 = lb >> 8;
    const int cnt = (hb > lb) ? (((hb + 255) >> 8) - t0) : 0;
    if (g < 0 && p < pre + cnt) { g = gi; tile = t0 + (p - pre); lo = lb; hi = hb; }
    pre += cnt;
  }
  if (g < 0) return;  // dead pair; uniform per block, before any barrier

  const int m0 = tile * 256;

  // A ring: 4 half-slots x (128 rows x 64 cols) = 64KB; half hi of tile tt
  // lives in slot (2*tt+hi)&3.  B ring: 4 half-slots x (64 x 64) = 32KB.
  __shared__ __align__(16) __hip_bfloat16 Ar[4][128 * 64];
  __shared__ __align__(16) __hip_bfloat16 Br[4][64 * 64];

  const __hip_bfloat16* wg = wb + (size_t)g * N_DIM * K_DIM;

  const int lane = threadIdx.x & 63;
  const int wid  = threadIdx.x >> 6;   // 0..7
  const int wm   = wid >> 1;           // 0..3 -> m offset 64
  const int wn   = wid & 1;            // 0..1 -> n offset 64

  // staging: chunk = 8 rows x 64 cols = 1KB per wave-load; lane -> +16B linear.
  // row&7 == srow -> XOR swizzle permutes the GLOBAL column block (rule 21).
  const int srow = lane >> 3;
  const int scol = ((lane & 7) ^ srow) * 8;

  // A half (16KB = 16 chunks): wave stages chunks {2*wid, 2*wid+1}.
  // B half (8KB  =  8 chunks): wave stages chunk wid.
  const __hip_bfloat16* aSrc0 = xb + (size_t)(m0 + srow) * K_DIM + scol;
  const __hip_bfloat16* bSrc0 = wg + (size_t)(n0 + srow) * K_DIM + scol;

  auto stageA = [&](int tt, int hi) {
    const int slot = (2 * tt + hi) & 3;
#pragma unroll
    for (int i = 0; i < 2; ++i) {
      const int ch = wid * 2 + i;
      const __hip_bfloat16* src = aSrc0 + (size_t)(hi * 128 + ch * 8) * K_DIM + tt * 64;
      __builtin_amdgcn_global_load_lds((gvoid*)src,
                                       (lvoid*)(&Ar[slot][ch * 512 + lane * 8]),
                                       16, 0, 0);
    }
  };
  auto stageB = [&](int tt, int hi) {
    const int slot = (2 * tt + hi) & 3;
    const __hip_bfloat16* src = bSrc0 + (size_t)(hi * 64 + wid * 8) * K_DIM + tt * 64;
    __builtin_amdgcn_global_load_lds((gvoid*)src,
                                     (lvoid*)(&Br[slot][wid * 512 + lane * 8]),
                                     16, 0, 0);
  };

  f32x4 acc[4][4] = {};  // [mf][nf]

  // ---- prologue: A[0](4 loads), B[0](2), A[1](4); wait A[0]+B[0] landed,
  // A[1] stays in flight; barrier makes landing visible to all waves.
  stageA(0, 0); stageA(0, 1);
  stageB(0, 0); stageB(0, 1);
  stageA(1, 0); stageA(1, 1);
  asm volatile("s_waitcnt vmcnt(4)" ::: "memory");
  __builtin_amdgcn_s_barrier();
  FENCE();

  const int ahalf = wm >> 1;            // wave's A half (0/1)
  const int arow0 = (wm & 1) * 64;      // row base within the half

  for (int kt = 0; kt < NT; ++kt) {
    const int sA = (2 * kt + ahalf) & 3;
    const int sB = (2 * kt + wn) & 3;
    short8 a[4][2];

#pragma unroll
    for (int nf = 0; nf < 4; ++nf) {
      // ---- ds_reads for this phase (pre-barrier)
      if (nf == 0) {
#pragma unroll
        for (int mf = 0; mf < 4; ++mf)
#pragma unroll
          for (int ks = 0; ks < 2; ++ks) {
            const int off = (((ks * 4 + (lane >> 4)) ^ (lane & 7)) * 8);
            a[mf][ks] = *reinterpret_cast<const short8*>(
                &Ar[sA][(arow0 + mf * 16 + (lane & 15)) * 64 + off]);
          }
      }
      short8 b0, b1;
      {
        const int row = nf * 16 + (lane & 15);
        const int o0  = (((0 * 4 + (lane >> 4)) ^ (lane & 7)) * 8);
        const int o1  = (((1 * 4 + (lane >> 4)) ^ (lane & 7)) * 8);
        b0 = *reinterpret_cast<const short8*>(&Br[sB][row * 64 + o0]);
        b1 = *reinterpret_cast<const short8*>(&Br[sB][row * 64 + o1]);
      }

      // ---- stage schedule (race rule: slot's last read >= 2 phases ago)
      if (nf == 1 && kt + 1 < NT) { stageB(kt + 1, 0); stageB(kt + 1, 1); }
      if (nf == 2 && kt + 2 < NT) { stageA(kt + 2, 0); }
      if (nf == 3) {
        if (kt + 2 < NT) stageA(kt + 2, 1);
        if (kt < NT - 2) {
          // leave A[kt+2]'s 4 loads in flight; everything older has landed
          asm volatile("s_waitcnt vmcnt(4)" ::: "memory");
        } else {
          asm volatile("s_waitcnt vmcnt(0)" ::: "memory");
        }
      }

      FENCE();
      __builtin_amdgcn_s_barrier();
      FENCE();

      __builtin_amdgcn_s_setprio(1);
#pragma unroll
      for (int mf = 0; mf < 4; ++mf) {
        acc[mf][nf] = __builtin_amdgcn_mfma_f32_16x16x32_bf16(
            a[mf][0], b0, acc[mf][nf], 0, 0, 0);
        acc[mf][nf] = __builtin_amdgcn_mfma_f32_16x16x32_bf16(
            a[mf][1], b1, acc[mf][nf], 0, 0, 0);
      }
      __builtin_amdgcn_s_setprio(0);

      FENCE();
      __builtin_amdgcn_s_barrier();
      FENCE();
    }
  }

  // ---- epilogue: C/D layout col=lane&15, row=(lane>>4)*4+reg [m89-verified];
  // store only rows in [lo,hi) — boundary tiles written disjointly per expert.
  const int quad = lane >> 4;
#pragma unroll
  for (int mf = 0; mf < 4; ++mf) {
    const int rbase = m0 + wm * 64 + mf * 16 + quad * 4;
#pragma unroll
    for (int r = 0; r < 4; ++r) {
      const int row = rbase + r;
      if (row < lo || row >= hi) continue;
#pragma unroll
      for (int nf = 0; nf < 4; ++nf) {
        const int col = n0 + wn * 64 + nf * 16 + (lane & 15);
        out[(size_t)row * N_DIM + col] = acc[mf][nf][r];
      }
    }
  }
}

// ---------------- fp32 fallback (only if d_ws < 48 MB; correctness-only) ----
__global__ __launch_bounds__(256) void fallback_kernel(
    const float* __restrict__ x, const float* __restrict__ w,
    const int* __restrict__ offs, float* __restrict__ out) {
  __shared__ float xs[K_DIM];
  const int t = blockIdx.y;
  int g = 0;
  while (g < G_DIM - 1 && offs[g] <= t) ++g;
  for (int i = threadIdx.x; i < K_DIM; i += blockDim.x)
    xs[i] = x[(size_t)t * K_DIM + i];
  __syncthreads();
  const int n = blockIdx.x * blockDim.x + threadIdx.x;
  const float* wr = w + ((size_t)g * N_DIM + n) * K_DIM;
  float s = 0.f;
  for (int k = 0; k < K_DIM; ++k) s += xs[k] * wr[k];
  out[(size_t)t * N_DIM + n] = s;
}

extern "C" void kernel_launch(void* const* d_in, const int* in_sizes, int n_in,
                              void* d_out, int out_size, void* d_ws, size_t ws_size,
                              hipStream_t stream) {
  const float* x    = (const float*)d_in[0];
  const float* w    = (const float*)d_in[1];
  const int*   offs = (const int*)d_in[2];
  float*       out  = (float*)d_out;

  const size_t x_elems = (size_t)T_DIM * K_DIM;            // 8.39M
  const size_t w_elems = (size_t)G_DIM * N_DIM * K_DIM;    // 16.78M
  const size_t need    = (x_elems + w_elems) * sizeof(__hip_bfloat16);  // 48 MiB

  if (ws_size < need) {
    fallback_kernel<<<dim3(N_DIM / 256, T_DIM), 256, 0, stream>>>(x, w, offs, out);
    return;
  }

  __hip_bfloat16* xb = (__hip_bfloat16*)d_ws;
  __hip_bfloat16* wb = xb + x_elems;

  const int n8x   = (int)(x_elems / 8);              // 1,048,576
  const int n8tot = (int)((x_elems + w_elems) / 8);  // 3,145,728
  cvt_kernel<<<4096, 256, 0, stream>>>(x, w, (ushort8*)xb, (ushort8*)wb,
                                       n8x, n8tot);

  grouped_gemm_kernel<<<dim3(16, MAX_PAIRS), 512, 0, stream>>>(
      xb, wb, offs, out);
}

// Round 5
// 186.339 us; speedup vs baseline: 1.1534x; 1.1534x over previous
//
#include <hip/hip_runtime.h>
#include <hip/hip_bf16.h>

// GroupLinear: out[t] = x[t] @ w[gid(t)].T
// T=8192, G=8, K=1024, N=2048; groups = contiguous token ranges (cum end-offs).
//
// R10 = R5 (best measured GEMM: 54us, 27% MfmaUtil) restored EXACTLY, plus two
// low-risk changes:
//  1. Vectorized epilogue: K=1024 -> only 16 K-iters, so R5's 64 scalar
//     global_store_dword/thread epilogue is ~15-20% of GEMM time (at K=4096 it
//     was ~5%). Now: per-wave LDS transpose (reusing staging LDS after the
//     final barrier; stride 68 floats -> 16B-aligned, 2-way bank conflicts =
//     free per m136) then 16 coalesced dwordx4 stores (256B/16-lane segment).
//     Within-wave only; WAR/RAW ordered via lgkmcnt(0)+sched_barrier (rule 18).
//  2. Pair-major XCD swizzle (R6/R8-measured: FETCH 84.5->47-57MB, time-neutral
//     or better): 1152 blocks = 8 XCD x 9 pairs x 16 n-blocks, bijective.
//  R6/R9 lesson: counted-vmcnt pipeline ports regressed twice (barrier-thin
//  phases, occupancy collapse). The 2-barrier + high-TLP structure stays.

#define T_DIM 8192
#define G_DIM 8
#define K_DIM 1024
#define N_DIM 2048
#define MAX_PAIRS 72  // 64 m-tiles + <=7 boundary duplicates, rounded up (%8==0)

using short8  = __attribute__((ext_vector_type(8))) short;   // 8 bf16
using f32x4   = __attribute__((ext_vector_type(4))) float;   // MFMA acc / vec io
using ushort8 = __attribute__((ext_vector_type(8))) unsigned short;

typedef __attribute__((address_space(1))) void gvoid;  // global
typedef __attribute__((address_space(3))) void lvoid;  // LDS

// ---------------- fp32 -> bf16 convert (grid-stride, 2x unroll, nt loads) ---
__global__ __launch_bounds__(256) void cvt_kernel(const float* __restrict__ x,
                                                  const float* __restrict__ w,
                                                  ushort8* __restrict__ xb,
                                                  ushort8* __restrict__ wb,
                                                  int n8x, int n8tot) {
  const int stride = gridDim.x * blockDim.x;
  for (int i = blockIdx.x * blockDim.x + threadIdx.x; i < n8tot; i += 2 * stride) {
#pragma unroll
    for (int u = 0; u < 2; ++u) {
      const int idx = i + u * stride;
      if (idx >= n8tot) break;
      const f32x4* s; ushort8* d; int j;
      if (idx < n8x) { s = (const f32x4*)x; d = xb; j = idx; }
      else           { s = (const f32x4*)w; d = wb; j = idx - n8x; }
      f32x4 v0 = __builtin_nontemporal_load(&s[2 * j]);
      f32x4 v1 = __builtin_nontemporal_load(&s[2 * j + 1]);
      ushort8 o;
      o[0] = __builtin_bit_cast(unsigned short, __float2bfloat16(v0[0]));
      o[1] = __builtin_bit_cast(unsigned short, __float2bfloat16(v0[1]));
      o[2] = __builtin_bit_cast(unsigned short, __float2bfloat16(v0[2]));
      o[3] = __builtin_bit_cast(unsigned short, __float2bfloat16(v0[3]));
      o[4] = __builtin_bit_cast(unsigned short, __float2bfloat16(v1[0]));
      o[5] = __builtin_bit_cast(unsigned short, __float2bfloat16(v1[1]));
      o[6] = __builtin_bit_cast(unsigned short, __float2bfloat16(v1[2]));
      o[7] = __builtin_bit_cast(unsigned short, __float2bfloat16(v1[3]));
      d[j] = o;
    }
  }
}

// ---------------- grouped bf16 GEMM, 128x128, R5 structure ------------------
__global__ __launch_bounds__(256, 4) void grouped_gemm_kernel(
    const __hip_bfloat16* __restrict__ xb,
    const __hip_bfloat16* __restrict__ wb,
    const int* __restrict__ offs,
    float* __restrict__ out) {
  // ---- pair-major XCD swizzle: v%8 = XCD; XCD c owns pairs [9c,9c+9) x 16 nb.
  const int v  = blockIdx.y * 16 + blockIdx.x;   // grid (16,72), 1152 blocks
  const int c  = v & 7;
  const int l  = v >> 3;                          // 0..143
  const int p  = c * 9 + (l % 9);                 // pair 0..71
  const int nb = l / 9;                           // n-block 0..15
  const int n0 = nb * 128;

  // ---- map pair p -> (expert g, m-tile) via prefix sum of tile spans
  int offv[G_DIM];
#pragma unroll
  for (int i = 0; i < G_DIM; ++i) offv[i] = offs[i];

  int g = -1, tile = 0, lo = 0, hi = 0, pre = 0;
#pragma unroll
  for (int gi = 0; gi < G_DIM; ++gi) {
    const int lb = gi ? offv[gi - 1] : 0;
    const int hb = offv[gi];
    const int t0 = lb >> 7;
    const int cnt = (hb > lb) ? (((hb + 127) >> 7) - t0) : 0;
    if (g < 0 && p < pre + cnt) { g = gi; tile = t0 + (p - pre); lo = lb; hi = hb; }
    pre += cnt;
  }
  if (g < 0) return;  // p >= total pairs (few dead blocks; before any barrier)

  const int m0 = tile * 128;

  // one contiguous block so the epilogue can reuse all 32KB as fp32 buffer
  __shared__ __align__(16) __hip_bfloat16 smem[2 * 128 * 64];
  __hip_bfloat16* As = smem;             // [m][k] swizzled, 16KB
  __hip_bfloat16* Bs = smem + 128 * 64;  // [n][k] swizzled, 16KB

  const __hip_bfloat16* wg = wb + (size_t)g * N_DIM * K_DIM;

  const int lane = threadIdx.x & 63;
  const int wid  = threadIdx.x >> 6;
  const int wm   = wid >> 1;   // wave row (0..1)
  const int wn   = wid & 1;    // wave col (0..1)

  // staging: chunk j = 8 rows x 64 cols = 1KB; lane l -> LDS base + l*16B.
  // row&7 == srow, so the XOR swizzle permutes the GLOBAL column block.
  const int srow = lane >> 3;                  // row within chunk
  const int scol = ((lane & 7) ^ srow) * 8;    // swizzled global col (elems)

  f32x4 acc[4][4] = {};

  for (int kk = 0; kk < K_DIM / 64; ++kk) {
    const int k0 = kk * 64;
#pragma unroll
    for (int i = 0; i < 4; ++i) {
      const int j   = wid * 4 + i;      // 0..15
      const int row = j * 8 + srow;
      const __hip_bfloat16* ga = xb + (size_t)(m0 + row) * K_DIM + k0 + scol;
      const __hip_bfloat16* gb = wg + (size_t)(n0 + row) * K_DIM + k0 + scol;
      __builtin_amdgcn_global_load_lds((gvoid*)ga, (lvoid*)(As + j * 512), 16, 0, 0);
      __builtin_amdgcn_global_load_lds((gvoid*)gb, (lvoid*)(Bs + j * 512), 16, 0, 0);
    }
    __syncthreads();

#pragma unroll
    for (int ks = 0; ks < 2; ++ks) {
      // global 16B-block index this lane needs: kb = ks*4 + (lane>>4)
      // fragment rows have row&7 == lane&7 -> swizzled offset:
      const int kb  = ks * 4 + (lane >> 4);
      const int off = ((kb ^ (lane & 7)) * 8);
      short8 a[4], b[4];
#pragma unroll
      for (int mt = 0; mt < 4; ++mt)
        a[mt] = *reinterpret_cast<const short8*>(
            As + (wm * 64 + mt * 16 + (lane & 15)) * 64 + off);
#pragma unroll
      for (int nt = 0; nt < 4; ++nt)
        b[nt] = *reinterpret_cast<const short8*>(
            Bs + (wn * 64 + nt * 16 + (lane & 15)) * 64 + off);
#pragma unroll
      for (int mt = 0; mt < 4; ++mt)
#pragma unroll
        for (int nt = 0; nt < 4; ++nt)
          acc[mt][nt] = __builtin_amdgcn_mfma_f32_16x16x32_bf16(
              a[mt], b[nt], acc[mt][nt], 0, 0, 0);
    }
    __syncthreads();
  }
  // final __syncthreads above: all waves done with As/Bs -> safe to reuse LDS.

  // ---- epilogue: C/D layout col=lane&15, row=(lane>>4)*4+reg [m89-verified].
  // Per-wave LDS transpose (stride 68 floats: 16B-aligned, 2-way conflicts
  // only) then coalesced dwordx4 stores; rows masked to [lo,hi) (boundary
  // tiles written disjointly per expert). Per-wave regions disjoint -> only
  // within-wave lgkm ordering needed (rule 18: follow asm wait w/ sched_barrier).
  {
    float* Cw = ((float*)smem) + wid * (16 * 68);  // 4 x 4352B = 17KB <= 32KB
    const int quad = lane >> 4;
    const int c16  = lane & 15;
#pragma unroll
    for (int mt = 0; mt < 4; ++mt) {
#pragma unroll
      for (int nt = 0; nt < 4; ++nt)
#pragma unroll
        for (int r = 0; r < 4; ++r)
          Cw[(quad * 4 + r) * 68 + nt * 16 + c16] = acc[mt][nt][r];
      asm volatile("s_waitcnt lgkmcnt(0)" ::: "memory");
      __builtin_amdgcn_sched_barrier(0);
      const int rbase = m0 + wm * 64 + mt * 16;
#pragma unroll
      for (int rr = 0; rr < 4; ++rr) {
        const int row = rbase + rr * 4 + quad;
        f32x4 vv = *reinterpret_cast<const f32x4*>(
            Cw + (rr * 4 + quad) * 68 + c16 * 4);
        if (row >= lo && row < hi) {
          __builtin_nontemporal_store(
              vv, reinterpret_cast<f32x4*>(
                      out + (size_t)row * N_DIM + n0 + wn * 64 + c16 * 4));
        }
      }
      asm volatile("s_waitcnt lgkmcnt(0)" ::: "memory");  // WAR vs next mt
      __builtin_amdgcn_sched_barrier(0);
    }
  }
}

// ---------------- fp32 fallback (only if d_ws < 48 MB; correctness-only) ----
__global__ __launch_bounds__(256) void fallback_kernel(
    const float* __restrict__ x, const float* __restrict__ w,
    const int* __restrict__ offs, float* __restrict__ out) {
  __shared__ float xs[K_DIM];
  const int t = blockIdx.y;
  int g = 0;
  while (g < G_DIM - 1 && offs[g] <= t) ++g;
  for (int i = threadIdx.x; i < K_DIM; i += blockDim.x)
    xs[i] = x[(size_t)t * K_DIM + i];
  __syncthreads();
  const int n = blockIdx.x * blockDim.x + threadIdx.x;
  const float* wr = w + ((size_t)g * N_DIM + n) * K_DIM;
  float s = 0.f;
  for (int k = 0; k < K_DIM; ++k) s += xs[k] * wr[k];
  out[(size_t)t * N_DIM + n] = s;
}

extern "C" void kernel_launch(void* const* d_in, const int* in_sizes, int n_in,
                              void* d_out, int out_size, void* d_ws, size_t ws_size,
                              hipStream_t stream) {
  const float* x    = (const float*)d_in[0];
  const float* w    = (const float*)d_in[1];
  const int*   offs = (const int*)d_in[2];
  float*       out  = (float*)d_out;

  const size_t x_elems = (size_t)T_DIM * K_DIM;            // 8.39M
  const size_t w_elems = (size_t)G_DIM * N_DIM * K_DIM;    // 16.78M
  const size_t need    = (x_elems + w_elems) * sizeof(__hip_bfloat16);  // 48 MiB

  if (ws_size < need) {
    fallback_kernel<<<dim3(N_DIM / 256, T_DIM), 256, 0, stream>>>(x, w, offs, out);
    return;
  }

  __hip_bfloat16* xb = (__hip_bfloat16*)d_ws;
  __hip_bfloat16* wb = xb + x_elems;

  const int n8x   = (int)(x_elems / 8);              // 1,048,576
  const int n8tot = (int)((x_elems + w_elems) / 8);  // 3,145,728
  cvt_kernel<<<4096, 256, 0, stream>>>(x, w, (ushort8*)xb, (ushort8*)wb,
                                       n8x, n8tot);

  grouped_gemm_kernel<<<dim3(16, MAX_PAIRS), 256, 0, stream>>>(
      xb, wb, offs, out);
}